// Round 4
// baseline (140.193 us; speedup 1.0000x reference)
//
#include <hip/hip_runtime.h>
#include <hip/hip_bf16.h>
#include <math.h>

#define HIDDEN 2048
#define NH 16
#define NKV 2
#define HD 128
#define CTX 4096
#define NL 36
#define EPS 1e-6f

#define CHUNK 128
#define NCHUNKS 32              /* CTX/CHUNK */
#define HPB 8                   /* Q heads per attn role (one KV head) */
#define NGRP 2                  /* NH/HPB  -> K/V read exactly once */
#define NBLK 256

/* ws layout (float offsets) */
#define WS_QKV  0               /* rows 0..2047 q, 2048..2303 k, 2304..2559 v */
#define WS_PML  2560            /* NH*NCHUNKS*2 = 1024 */
#define WS_PACC 3584            /* NH*NCHUNKS*128 = 65536 */
#define WS_CTX  69120           /* 2048 */
#define WS_SYNC 71168           /* 8 ints */

#define RSQRT_HD 0.08838834764831845f  /* 1/sqrt(128) */

__device__ __forceinline__ float dot4(float4 a, float4 b) {
    return a.x*b.x + a.y*b.y + a.z*b.z + a.w*b.w;
}

// Zero the barrier counters every call (ws is poisoned once, never restored).
__global__ void init_sync(float* __restrict__ ws) {
    int* s = (int*)(ws + WS_SYNC);
    if (threadIdx.x < 8) s[threadIdx.x] = 0;
}

__device__ __forceinline__ void gridbar(int* cnt, int t) {
    __syncthreads();
    if (t == 0) {
        __hip_atomic_fetch_add(cnt, 1, __ATOMIC_ACQ_REL, __HIP_MEMORY_SCOPE_AGENT);
        while (__hip_atomic_load(cnt, __ATOMIC_ACQUIRE, __HIP_MEMORY_SCOPE_AGENT) < NBLK)
            __builtin_amdgcn_s_sleep(2);
    }
    __syncthreads();
}

__global__ __launch_bounds__(256, 2) void fused_kernel(
    const float* __restrict__ x, const float* __restrict__ lnw,
    const float* __restrict__ wq, const float* __restrict__ bq,
    const float* __restrict__ wk, const float* __restrict__ bk,
    const float* __restrict__ wv, const float* __restrict__ bv,
    const float* __restrict__ wo, const float* __restrict__ kvc,
    const int* __restrict__ curpos, const float* __restrict__ hidden,
    float* __restrict__ ws, float* __restrict__ out)
{
    const int t = threadIdx.x;
    const int lane = t & 63, wid = t >> 6;
    const int b = blockIdx.x;
    int* cnt = (int*)(ws + WS_SYNC);
    const int pos = curpos[0];

    __shared__ float redS[4];
    __shared__ float redR[4][10];
    __shared__ float tab[128];
    __shared__ float kf[HD];
    __shared__ float qr[HPB][HD];
    __shared__ float sc[HPB][CHUNK];
    __shared__ float ctxh[8][HPB][HD];
    __shared__ float ctx2[HIDDEN];

    // ================= Phase A: fused QKV matvec (10 rows/block) ==========
    // weight prefetch first -> 80 KB/block in flight immediately
    float4 qw0[10], qw1[10];
    #pragma unroll
    for (int r = 0; r < 10; ++r) {
        const int R = b * 10 + r;
        const float* w;
        if (R < 2048)      w = wq + (size_t)R * HIDDEN;
        else if (R < 2304) w = wk + (size_t)(R - 2048) * HIDDEN;
        else               w = wv + (size_t)(R - 2304) * HIDDEN;
        qw0[r] = ((const float4*)w)[t * 2];
        qw1[r] = ((const float4*)w)[t * 2 + 1];
    }

    // RMSNorm (block-wide, x/lnw tiny + L2-resident)
    float4 xa = ((const float4*)x)[t * 2];
    float4 xb = ((const float4*)x)[t * 2 + 1];
    float ss = dot4(xa, xa) + dot4(xb, xb);
    #pragma unroll
    for (int m = 32; m; m >>= 1) ss += __shfl_xor(ss, m);
    if (lane == 0) redS[wid] = ss;
    __syncthreads();
    const float inv = rsqrtf((redS[0] + redS[1] + redS[2] + redS[3]) * (1.f / HIDDEN) + EPS);
    float4 la = ((const float4*)lnw)[t * 2];
    float4 lb = ((const float4*)lnw)[t * 2 + 1];
    float4 nxa, nxb;
    nxa.x = xa.x * inv * la.x; nxa.y = xa.y * inv * la.y;
    nxa.z = xa.z * inv * la.z; nxa.w = xa.w * inv * la.w;
    nxb.x = xb.x * inv * lb.x; nxb.y = xb.y * inv * lb.y;
    nxb.z = xb.z * inv * lb.z; nxb.w = xb.w * inv * lb.w;

    // 10 block-wide dots
    float p[10];
    #pragma unroll
    for (int r = 0; r < 10; ++r)
        p[r] = dot4(qw0[r], nxa) + dot4(qw1[r], nxb);
    #pragma unroll
    for (int r = 0; r < 10; ++r)
        #pragma unroll
        for (int m = 32; m; m >>= 1) p[r] += __shfl_xor(p[r], m);
    if (lane == 0)
        #pragma unroll
        for (int r = 0; r < 10; ++r) redR[wid][r] = p[r];
    __syncthreads();
    if (t < 10) {
        const int R = b * 10 + t;
        float bias;
        if (R < 2048)      bias = bq[R];
        else if (R < 2304) bias = bk[R - 2048];
        else               bias = bv[R - 2304];
        ws[R] = redR[0][t] + redR[1][t] + redR[2][t] + redR[3][t] + bias;
    }

    gridbar(cnt + 0, t);

    // ================= Phase B: attention (blocks 0..63; K/V read once) ===
    bool attnRole = false;
    int grp = 0, c = 0, start = 0, nvalid = 0;
    if (b < NGRP * NCHUNKS) {
        grp = b >> 5; c = b & 31; start = c * CHUNK;
        if (start <= pos) { attnRole = true; nvalid = min(CHUNK, pos + 1 - start); }
    }

    if (attnRole) {
        const int h0 = grp * HPB, kvh = grp;
        const float* kc = kvc + (size_t)kvh * CTX * HD;
        const float* vc = kvc + (size_t)(NL * NKV + kvh) * CTX * HD;

        // RoPE table (fp64 angle + range-reduce, then sincosf)
        if (t < 64) {
            double e = (double)t * (1.0 / 64.0);
            double invf = exp2(-19.931568569324174087 * e);   /* 1e6^-e */
            double a = (double)pos * invf;
            a -= 6.2831853071795864769 * floor(a * 0.15915494309189533577);
            float s, cs;
            sincosf((float)a, &s, &cs);
            tab[t] = cs; tab[64 + t] = s;
        }
        __syncthreads();
        if (t < 128) {  // fresh k, roped
            const float* kr = ws + 2048 + (size_t)kvh * HD;
            float kvd = kr[t], kp = kr[t ^ 64];
            float r = (t < 64) ? -kp : kp;
            kf[t] = kvd * tab[t & 63] + r * tab[64 + (t & 63)];
        }
        #pragma unroll
        for (int i = 0; i < 4; ++i) {  // q RoPE + scale (8 heads x 128)
            int e = t + i * 256;
            int hh = e >> 7, d = e & 127;
            const float* q = ws + (size_t)(h0 + hh) * HD;
            float qv = q[d], qp = q[d ^ 64];
            float r = (d < 64) ? -qp : qp;
            qr[hh][d] = (qv * tab[d & 63] + r * tab[64 + (d & 63)]) * RSQRT_HD;
        }
        __syncthreads();

        // batch-issue K tile then V tile (~128 KB/block in flight)
        const int g16 = t >> 4, li = t & 15;
        float4 ka[8], kb[8];
        #pragma unroll
        for (int it = 0; it < 8; ++it) {
            const int pp = start + it * 16 + g16;   // < CTX, always in-bounds
            const float4* kp = (const float4*)(kc + (size_t)pp * HD + li * 8);
            ka[it] = kp[0]; kb[it] = kp[1];
        }
        const int half = t >> 5, q4 = t & 31;
        float4 vv[16];
        #pragma unroll
        for (int i = 0; i < 16; ++i) {
            const int pp = start + i * 8 + half;
            vv[i] = ((const float4*)(vc + (size_t)pp * HD))[q4];
        }
        float4 fv = ((const float4*)(ws + 2304 + (size_t)kvh * HD))[q4];

        // scores: two passes of 4 heads over the same K registers
        #pragma unroll
        for (int P = 0; P < 2; ++P) {
            float4 qa[4], qb[4];
            #pragma unroll
            for (int hh = 0; hh < 4; ++hh) {
                qa[hh] = *(const float4*)&qr[P * 4 + hh][li * 8];
                qb[hh] = *(const float4*)&qr[P * 4 + hh][li * 8 + 4];
            }
            #pragma unroll
            for (int it = 0; it < 8; ++it) {
                const int pl = it * 16 + g16;
                float4 A = ka[it], B = kb[it];
                if (start + pl == pos) {
                    A = *(const float4*)&kf[li * 8];
                    B = *(const float4*)&kf[li * 8 + 4];
                }
                float s0 = dot4(qa[0], A) + dot4(qb[0], B);
                float s1 = dot4(qa[1], A) + dot4(qb[1], B);
                float s2 = dot4(qa[2], A) + dot4(qb[2], B);
                float s3 = dot4(qa[3], A) + dot4(qb[3], B);
                #pragma unroll
                for (int m = 1; m < 16; m <<= 1) {
                    s0 += __shfl_xor(s0, m); s1 += __shfl_xor(s1, m);
                    s2 += __shfl_xor(s2, m); s3 += __shfl_xor(s3, m);
                }
                if (pl < nvalid && li == 0) {
                    sc[P * 4 + 0][pl] = s0; sc[P * 4 + 1][pl] = s1;
                    sc[P * 4 + 2][pl] = s2; sc[P * 4 + 3][pl] = s3;
                }
            }
        }
        // zero invalid tail so V-FMA runs unmasked
        #pragma unroll
        for (int i = 0; i < 4; ++i) {
            int e = t + i * 256;
            int hh = e >> 7, pl = e & 127;
            if (pl >= nvalid) sc[hh][pl] = 0.f;
        }
        __syncthreads();

        // softmax stats: wave wid -> heads wid, wid+4
        #pragma unroll
        for (int pass = 0; pass < 2; ++pass) {
            const int hh = wid + pass * 4;
            float m = -INFINITY;
            for (int pp = lane; pp < nvalid; pp += 64) m = fmaxf(m, sc[hh][pp]);
            #pragma unroll
            for (int mm = 32; mm; mm >>= 1) m = fmaxf(m, __shfl_xor(m, mm));
            float l = 0.f;
            for (int pp = lane; pp < nvalid; pp += 64) {
                float e = expf(sc[hh][pp] - m);
                sc[hh][pp] = e;
                l += e;
            }
            #pragma unroll
            for (int mm = 32; mm; mm >>= 1) l += __shfl_xor(l, mm);
            if (lane == 0) {
                ws[WS_PML + ((size_t)(h0 + hh) * NCHUNKS + c) * 2]     = m;
                ws[WS_PML + ((size_t)(h0 + hh) * NCHUNKS + c) * 2 + 1] = l;
            }
        }
        __syncthreads();

        // ctx partial from register-resident V: two passes of 4 heads
        #pragma unroll
        for (int P = 0; P < 2; ++P) {
            float4 a[4];
            #pragma unroll
            for (int hh = 0; hh < 4; ++hh) a[hh] = make_float4(0.f, 0.f, 0.f, 0.f);
            #pragma unroll
            for (int i = 0; i < 16; ++i) {
                const int pl = i * 8 + half;
                float4 xv = (start + pl == pos) ? fv : vv[i];
                #pragma unroll
                for (int hh = 0; hh < 4; ++hh) {
                    float w = sc[P * 4 + hh][pl];
                    a[hh].x += w * xv.x; a[hh].y += w * xv.y;
                    a[hh].z += w * xv.z; a[hh].w += w * xv.w;
                }
            }
            #pragma unroll
            for (int hh = 0; hh < 4; ++hh)
                *(float4*)&ctxh[half][P * 4 + hh][q4 * 4] = a[hh];
        }
        __syncthreads();

        #pragma unroll
        for (int i = 0; i < 4; ++i) {
            int e = t + i * 256;
            int hh = e >> 7, d = e & 127;
            float s = 0.f;
            #pragma unroll
            for (int hf = 0; hf < 8; ++hf) s += ctxh[hf][hh][d];
            ws[WS_PACC + ((size_t)(h0 + hh) * NCHUNKS + c) * 128 + d] = s;
        }
    }

    // wo prefetch (all blocks) — streams during attn spin for non-attn blocks
    const int row0 = b * 8 + wid * 2;
    const float4* w04 = (const float4*)(wo + (size_t)row0 * HIDDEN);
    const float4* w14 = (const float4*)(wo + (size_t)(row0 + 1) * HIDDEN);
    float4 u[8], v[8];
    #pragma unroll
    for (int j = 0; j < 8; ++j) { u[j] = w04[j * 64 + lane]; v[j] = w14[j * 64 + lane]; }

    gridbar(cnt + 1, t);

    // ================= combine (blocks 0..15, one head each) ==============
    if (b < NH && t < 128) {
        const int h = b;
        const int nc = pos / CHUNK + 1;
        float M = -INFINITY;
        for (int c2 = 0; c2 < nc; ++c2)
            M = fmaxf(M, ws[WS_PML + ((size_t)h * NCHUNKS + c2) * 2]);
        float L = 0.f, acc = 0.f;
        for (int c2 = 0; c2 < nc; ++c2) {
            float mm = ws[WS_PML + ((size_t)h * NCHUNKS + c2) * 2];
            float ll = ws[WS_PML + ((size_t)h * NCHUNKS + c2) * 2 + 1];
            float w = expf(mm - M);
            L += w * ll;
            acc += w * ws[WS_PACC + ((size_t)h * NCHUNKS + c2) * 128 + t];
        }
        ws[WS_CTX + h * HD + t] = acc / L;
    }

    gridbar(cnt + 2, t);

    // ================= Phase C: out proj + residual =======================
    ((float4*)ctx2)[t * 2]     = ((const float4*)(ws + WS_CTX))[t * 2];
    ((float4*)ctx2)[t * 2 + 1] = ((const float4*)(ws + WS_CTX))[t * 2 + 1];
    __syncthreads();

    const float4* c4 = (const float4*)ctx2;
    float a0 = 0.f, a1 = 0.f;
    #pragma unroll
    for (int j = 0; j < 8; ++j) {
        float4 n = c4[j * 64 + lane];
        a0 += dot4(u[j], n);
        a1 += dot4(v[j], n);
    }
    #pragma unroll
    for (int m = 32; m; m >>= 1) { a0 += __shfl_xor(a0, m); a1 += __shfl_xor(a1, m); }
    if (lane == 0) {
        out[row0]     = hidden[row0]     + a0;
        out[row0 + 1] = hidden[row0 + 1] + a1;
    }
}

extern "C" void kernel_launch(void* const* d_in, const int* in_sizes, int n_in,
                              void* d_out, int out_size, void* d_ws, size_t ws_size,
                              hipStream_t stream)
{
    const float* hidden = (const float*)d_in[0];
    const int*   cur    = (const int*)d_in[3];
    const float* lnw    = (const float*)d_in[4];
    const float* wq     = (const float*)d_in[5];
    const float* bq     = (const float*)d_in[6];
    const float* wk     = (const float*)d_in[7];
    const float* bk     = (const float*)d_in[8];
    const float* wv     = (const float*)d_in[9];
    const float* bv     = (const float*)d_in[10];
    const float* wo     = (const float*)d_in[11];
    const float* kv     = (const float*)d_in[12];
    float* ws  = (float*)d_ws;
    float* out = (float*)d_out;

    init_sync<<<dim3(1), dim3(64), 0, stream>>>(ws);
    fused_kernel<<<dim3(NBLK), dim3(256), 0, stream>>>(
        hidden, lnw, wq, bq, wk, bk, wv, bv, wo, kv, cur, hidden, ws, out);
}

// Round 5
// 94.259 us; speedup vs baseline: 1.4873x; 1.4873x over previous
//
#include <hip/hip_runtime.h>
#include <hip/hip_bf16.h>
#include <math.h>

#define HIDDEN 2048
#define NH 16
#define NKV 2
#define HD 128
#define CTX 4096
#define NL 36
#define EPS 1e-6f

#define CHUNK 128
#define NCHUNKS 32              /* CTX/CHUNK */
#define HPB 8                   /* Q heads per attn block (= one KV head) */
#define NATT 64                 /* NKV * NCHUNKS attn-role blocks */
#define NBLK 256

/* ws layout (float offsets) */
#define WS_QKV  0               /* rows 0..2047 q, 2048..2303 k, 2304..2559 v */
#define WS_PML  2560            /* NH*NCHUNKS*2 = 1024 */
#define WS_PACC 3584            /* NH*NCHUNKS*128 = 65536 */
#define WS_SYNC 69200           /* 8 ints */

#define RSQRT_HD 0.08838834764831845f  /* 1/sqrt(128) */

__device__ __forceinline__ float dot4(float4 a, float4 b) {
    return a.x*b.x + a.y*b.y + a.z*b.z + a.w*b.w;
}

// Zero barrier counters every call (ws is poisoned once, never restored).
__global__ void init_sync(float* __restrict__ ws) {
    int* s = (int*)(ws + WS_SYNC);
    if (threadIdx.x < 8) s[threadIdx.x] = 0;
}

__device__ __forceinline__ void gridbar(int* cnt, int t) {
    __syncthreads();
    if (t == 0) {
        __hip_atomic_fetch_add(cnt, 1, __ATOMIC_ACQ_REL, __HIP_MEMORY_SCOPE_AGENT);
        while (__hip_atomic_load(cnt, __ATOMIC_ACQUIRE, __HIP_MEMORY_SCOPE_AGENT) < NBLK)
            __builtin_amdgcn_s_sleep(1);
    }
    __syncthreads();
}

__global__ __launch_bounds__(256, 1) void fused_kernel(
    const float* __restrict__ x, const float* __restrict__ lnw,
    const float* __restrict__ wq, const float* __restrict__ bq,
    const float* __restrict__ wk, const float* __restrict__ bk,
    const float* __restrict__ wv, const float* __restrict__ bv,
    const float* __restrict__ wo, const float* __restrict__ kvc,
    const int* __restrict__ curpos, float* __restrict__ ws,
    float* __restrict__ out)
{
    const int t = threadIdx.x;
    const int lane = t & 63, wid = t >> 6;
    const int b = blockIdx.x;
    int* cnt = (int*)(ws + WS_SYNC);
    const int pos = curpos[0];

    __shared__ float redS[4];
    __shared__ float redR[4][10];
    __shared__ float tab[128];
    __shared__ float kf[HD];
    __shared__ float qr[HPB][HD];
    __shared__ float sc[HPB][CHUNK];
    __shared__ float ctxh[8][HPB][HD];
    __shared__ float ctx2[HIDDEN];

    // attn role geometry (block-uniform)
    const int grp = b >> 5, c = b & 31, start = c * CHUNK;
    const bool attnRole = (b < NATT) && (start <= pos);
    const int nvalid = attnRole ? min(CHUNK, pos + 1 - start) : 0;
    const float* kc = kvc + (size_t)grp * CTX * HD;
    const float* vc = kvc + (size_t)(NL * NKV + grp) * CTX * HD;

    // ---------------- issue loads in consumption order --------------------
    // (1) x / lnw (needed first, RMSNorm)
    float4 xa = ((const float4*)x)[t * 2];
    float4 xb = ((const float4*)x)[t * 2 + 1];
    float4 la = ((const float4*)lnw)[t * 2];
    float4 lb = ((const float4*)lnw)[t * 2 + 1];

    // (2) qkv weight rows: 10 rows/block, 80 KB in flight
    float4 qw0[10], qw1[10];
    #pragma unroll
    for (int r = 0; r < 10; ++r) {
        const int R = b * 10 + r;
        const float* w;
        if (R < 2048)      w = wq + (size_t)R * HIDDEN;
        else if (R < 2304) w = wk + (size_t)(R - 2048) * HIDDEN;
        else               w = wv + (size_t)(R - 2304) * HIDDEN;
        qw0[r] = ((const float4*)w)[t * 2];
        qw1[r] = ((const float4*)w)[t * 2 + 1];
    }

    // (3) K tile (attn blocks): stays in flight through phase A
    const int g16 = t >> 4, li = t & 15;
    float4 ka[8], kb[8];
    if (attnRole) {
        #pragma unroll
        for (int it = 0; it < 8; ++it) {
            const int pp = start + it * 16 + g16;   // < CTX, always in-bounds
            const float4* kp = (const float4*)(kc + (size_t)pp * HD + li * 8);
            ka[it] = kp[0]; kb[it] = kp[1];
        }
    }

    // ---------------- Phase A: RMSNorm + fused QKV matvec -----------------
    float ss = dot4(xa, xa) + dot4(xb, xb);
    #pragma unroll
    for (int m = 32; m; m >>= 1) ss += __shfl_xor(ss, m);
    if (lane == 0) redS[wid] = ss;
    __syncthreads();
    const float inv = rsqrtf((redS[0] + redS[1] + redS[2] + redS[3]) * (1.f / HIDDEN) + EPS);
    float4 nxa, nxb;
    nxa.x = xa.x * inv * la.x; nxa.y = xa.y * inv * la.y;
    nxa.z = xa.z * inv * la.z; nxa.w = xa.w * inv * la.w;
    nxb.x = xb.x * inv * lb.x; nxb.y = xb.y * inv * lb.y;
    nxb.z = xb.z * inv * lb.z; nxb.w = xb.w * inv * lb.w;

    float p[10];
    #pragma unroll
    for (int r = 0; r < 10; ++r)
        p[r] = dot4(qw0[r], nxa) + dot4(qw1[r], nxb);
    #pragma unroll
    for (int r = 0; r < 10; ++r)
        #pragma unroll
        for (int m = 32; m; m >>= 1) p[r] += __shfl_xor(p[r], m);
    if (lane == 0)
        #pragma unroll
        for (int r = 0; r < 10; ++r) redR[wid][r] = p[r];
    __syncthreads();
    if (t < 10) {
        const int R = b * 10 + t;
        float bias;
        if (R < 2048)      bias = bq[R];
        else if (R < 2304) bias = bk[R - 2048];
        else               bias = bv[R - 2304];
        ws[R] = redR[0][t] + redR[1][t] + redR[2][t] + redR[3][t] + bias;
    }

    gridbar(cnt + 0, t);

    // ---------------- Phase B: attention (blocks 0..63, K/V once) ---------
    if (attnRole) {
        const int h0 = grp * HPB;

        // RoPE table: fp64 angle + range-reduce (proven numerics), cheap
        if (t < 64) {
            double e = (double)t * (1.0 / 64.0);
            double invf = exp2(-19.931568569324174087 * e);   /* 1e6^-e */
            double a = (double)pos * invf;
            a -= 6.2831853071795864769 * floor(a * 0.15915494309189533577);
            float s, cs;
            sincosf((float)a, &s, &cs);
            tab[t] = cs; tab[64 + t] = s;
        }
        __syncthreads();
        if (t < 128) {  // fresh k, roped
            const float* kr = ws + 2048 + (size_t)grp * HD;
            float kvd = kr[t], kp = kr[t ^ 64];
            float r = (t < 64) ? -kp : kp;
            kf[t] = kvd * tab[t & 63] + r * tab[64 + (t & 63)];
        }
        #pragma unroll
        for (int i = 0; i < 4; ++i) {  // q RoPE + scale (8 heads x 128)
            int e = t + i * 256;
            int hh = e >> 7, d = e & 127;
            const float* q = ws + (size_t)(h0 + hh) * HD;
            float qv = q[d], qp = q[d ^ 64];
            float r = (d < 64) ? -qp : qp;
            qr[hh][d] = (qv * tab[d & 63] + r * tab[64 + (d & 63)]) * RSQRT_HD;
        }
        __syncthreads();

        // V tile issue (stays outstanding through the score phase)
        const int half = t >> 5, q4 = t & 31;
        float4 vv[16];
        #pragma unroll
        for (int i = 0; i < 16; ++i) {
            const int pp = start + i * 8 + half;
            vv[i] = ((const float4*)(vc + (size_t)pp * HD))[q4];
        }
        float4 fv = ((const float4*)(ws + 2304 + (size_t)grp * HD))[q4];

        // scores: two passes of 4 heads over the same K registers
        #pragma unroll
        for (int P = 0; P < 2; ++P) {
            float4 qa[4], qb[4];
            #pragma unroll
            for (int hh = 0; hh < 4; ++hh) {
                qa[hh] = *(const float4*)&qr[P * 4 + hh][li * 8];
                qb[hh] = *(const float4*)&qr[P * 4 + hh][li * 8 + 4];
            }
            #pragma unroll
            for (int it = 0; it < 8; ++it) {
                const int pl = it * 16 + g16;
                float4 A = ka[it], B = kb[it];
                if (start + pl == pos) {
                    A = *(const float4*)&kf[li * 8];
                    B = *(const float4*)&kf[li * 8 + 4];
                }
                float s0 = dot4(qa[0], A) + dot4(qb[0], B);
                float s1 = dot4(qa[1], A) + dot4(qb[1], B);
                float s2 = dot4(qa[2], A) + dot4(qb[2], B);
                float s3 = dot4(qa[3], A) + dot4(qb[3], B);
                #pragma unroll
                for (int m = 1; m < 16; m <<= 1) {
                    s0 += __shfl_xor(s0, m); s1 += __shfl_xor(s1, m);
                    s2 += __shfl_xor(s2, m); s3 += __shfl_xor(s3, m);
                }
                if (pl < nvalid && li == 0) {
                    sc[P * 4 + 0][pl] = s0; sc[P * 4 + 1][pl] = s1;
                    sc[P * 4 + 2][pl] = s2; sc[P * 4 + 3][pl] = s3;
                }
            }
        }
        #pragma unroll
        for (int i = 0; i < 4; ++i) {   // zero invalid tail
            int e = t + i * 256;
            int hh = e >> 7, pl = e & 127;
            if (pl >= nvalid) sc[hh][pl] = 0.f;
        }
        __syncthreads();

        // softmax stats: wave wid -> heads wid, wid+4
        #pragma unroll
        for (int pass = 0; pass < 2; ++pass) {
            const int hh = wid + pass * 4;
            float m = -INFINITY;
            for (int pp = lane; pp < nvalid; pp += 64) m = fmaxf(m, sc[hh][pp]);
            #pragma unroll
            for (int mm = 32; mm; mm >>= 1) m = fmaxf(m, __shfl_xor(m, mm));
            float l = 0.f;
            for (int pp = lane; pp < nvalid; pp += 64) {
                float e = expf(sc[hh][pp] - m);
                sc[hh][pp] = e;
                l += e;
            }
            #pragma unroll
            for (int mm = 32; mm; mm >>= 1) l += __shfl_xor(l, mm);
            if (lane == 0) {
                ws[WS_PML + ((size_t)(h0 + hh) * NCHUNKS + c) * 2]     = m;
                ws[WS_PML + ((size_t)(h0 + hh) * NCHUNKS + c) * 2 + 1] = l;
            }
        }
        __syncthreads();

        // ctx partial from register-resident V
        #pragma unroll
        for (int P = 0; P < 2; ++P) {
            float4 a[4];
            #pragma unroll
            for (int hh = 0; hh < 4; ++hh) a[hh] = make_float4(0.f, 0.f, 0.f, 0.f);
            #pragma unroll
            for (int i = 0; i < 16; ++i) {
                const int pl = i * 8 + half;
                float4 xv = (start + pl == pos) ? fv : vv[i];
                #pragma unroll
                for (int hh = 0; hh < 4; ++hh) {
                    float w = sc[P * 4 + hh][pl];
                    a[hh].x += w * xv.x; a[hh].y += w * xv.y;
                    a[hh].z += w * xv.z; a[hh].w += w * xv.w;
                }
            }
            #pragma unroll
            for (int hh = 0; hh < 4; ++hh)
                *(float4*)&ctxh[half][P * 4 + hh][q4 * 4] = a[hh];
        }
        __syncthreads();

        #pragma unroll
        for (int i = 0; i < 4; ++i) {
            int e = t + i * 256;
            int hh = e >> 7, d = e & 127;
            float s = 0.f;
            #pragma unroll
            for (int hf = 0; hf < 8; ++hf) s += ctxh[hf][hh][d];
            ws[WS_PACC + ((size_t)(h0 + hh) * NCHUNKS + c) * 128 + d] = s;
        }
    }

    // wo hoist: non-attn blocks reach this immediately after bar(0) and
    // stream the 16MB while attn blocks compute.
    const int row0 = b * 8 + wid * 2;
    const float4* w04 = (const float4*)(wo + (size_t)row0 * HIDDEN);
    const float4* w14 = (const float4*)(wo + (size_t)(row0 + 1) * HIDDEN);
    float4 u[8], v[8];
    #pragma unroll
    for (int j = 0; j < 8; ++j) { u[j] = w04[j * 64 + lane]; v[j] = w14[j * 64 + lane]; }

    gridbar(cnt + 1, t);

    // ---------------- combine (redundant per block) -----------------------
    {
        const int nc = pos / CHUNK + 1;
        const int h = t >> 4, sub = t & 15;
        float M = -INFINITY;
        for (int c2 = 0; c2 < nc; ++c2)
            M = fmaxf(M, ws[WS_PML + ((size_t)h * NCHUNKS + c2) * 2]);
        float L = 0.f;
        float4 acc0 = make_float4(0.f,0.f,0.f,0.f), acc1 = make_float4(0.f,0.f,0.f,0.f);
        for (int c2 = 0; c2 < nc; ++c2) {
            float mm = ws[WS_PML + ((size_t)h * NCHUNKS + c2) * 2];
            float ll = ws[WS_PML + ((size_t)h * NCHUNKS + c2) * 2 + 1];
            float w = expf(mm - M);
            L += w * ll;
            const float4* pa = (const float4*)(ws + WS_PACC + ((size_t)h * NCHUNKS + c2) * 128 + sub * 8);
            float4 p0 = pa[0], p1 = pa[1];
            acc0.x += w*p0.x; acc0.y += w*p0.y; acc0.z += w*p0.z; acc0.w += w*p0.w;
            acc1.x += w*p1.x; acc1.y += w*p1.y; acc1.z += w*p1.z; acc1.w += w*p1.w;
        }
        float invL = 1.f / L;
        acc0.x *= invL; acc0.y *= invL; acc0.z *= invL; acc0.w *= invL;
        acc1.x *= invL; acc1.y *= invL; acc1.z *= invL; acc1.w *= invL;
        *(float4*)&ctx2[h * HD + sub * 8]     = acc0;
        *(float4*)&ctx2[h * HD + sub * 8 + 4] = acc1;
    }
    __syncthreads();

    // ---------------- Phase C: out proj + residual ------------------------
    const float4* c4 = (const float4*)ctx2;
    float a0 = 0.f, a1 = 0.f;
    #pragma unroll
    for (int j = 0; j < 8; ++j) {
        float4 n = c4[j * 64 + lane];
        a0 += dot4(u[j], n);
        a1 += dot4(v[j], n);
    }
    #pragma unroll
    for (int m = 32; m; m >>= 1) { a0 += __shfl_xor(a0, m); a1 += __shfl_xor(a1, m); }
    if (lane == 0) {
        out[row0]     = x[row0]     + a0;
        out[row0 + 1] = x[row0 + 1] + a1;
    }
}

extern "C" void kernel_launch(void* const* d_in, const int* in_sizes, int n_in,
                              void* d_out, int out_size, void* d_ws, size_t ws_size,
                              hipStream_t stream)
{
    const float* hidden = (const float*)d_in[0];
    const int*   cur    = (const int*)d_in[3];
    const float* lnw    = (const float*)d_in[4];
    const float* wq     = (const float*)d_in[5];
    const float* bq     = (const float*)d_in[6];
    const float* wk     = (const float*)d_in[7];
    const float* bk     = (const float*)d_in[8];
    const float* wv     = (const float*)d_in[9];
    const float* bv     = (const float*)d_in[10];
    const float* wo     = (const float*)d_in[11];
    const float* kv     = (const float*)d_in[12];
    float* ws  = (float*)d_ws;
    float* out = (float*)d_out;

    init_sync<<<dim3(1), dim3(64), 0, stream>>>(ws);
    fused_kernel<<<dim3(NBLK), dim3(256), 0, stream>>>(
        hidden, lnw, wq, bq, wk, bk, wv, bv, wo, kv, cur, ws, out);
}

// Round 6
// 47.474 us; speedup vs baseline: 2.9530x; 1.9855x over previous
//
#include <hip/hip_runtime.h>
#include <hip/hip_bf16.h>
#include <math.h>

#define HIDDEN 2048
#define NH 16
#define NKV 2
#define HD 128
#define CTX 4096
#define NL 36
#define EPS 1e-6f

#define CHUNK 64
#define NCHUNKS 64              /* CTX/CHUNK */
#define HPB 8                   /* Q heads per attn block (= one KV head) */
#define NATT 128                /* NKV * NCHUNKS */

/* ws layout (float offsets) */
#define WS_QKV  0               /* rows 0..2047 q, 2048..2303 k, 2304..2559 v */
#define WS_TAB  2560            /* cos[64], sin[64] */
#define WS_PML  2688            /* NH*NCHUNKS*2 = 2048 */
#define WS_PACC 4736            /* NH*NCHUNKS*128 = 131072 */

#define RSQRT_HD 0.08838834764831845f  /* 1/sqrt(128) */

__device__ __forceinline__ float dot4(float4 a, float4 b) {
    return a.x*b.x + a.y*b.y + a.z*b.z + a.w*b.w;
}

// ------------------------------------------------- K1: QKV (256 blocks)
// 10 rows/block of the fused [wq;wk;wv] matvec, block-wide dots.
// Block 0 additionally computes the RoPE table (overlaps its load wait).
__global__ __launch_bounds__(256, 1) void qkv_kernel(
    const float* __restrict__ x, const float* __restrict__ lnw,
    const float* __restrict__ wq, const float* __restrict__ bq,
    const float* __restrict__ wk, const float* __restrict__ bk,
    const float* __restrict__ wv, const float* __restrict__ bv,
    const int* __restrict__ curpos, float* __restrict__ ws)
{
    const int t = threadIdx.x;
    const int lane = t & 63, wid = t >> 6;
    const int b = blockIdx.x;

    __shared__ float redS[4];
    __shared__ float redR[4][10];

    // issue loads first: x/lnw then 10 weight rows (80 KB/block in flight)
    float4 xa = ((const float4*)x)[t * 2];
    float4 xb = ((const float4*)x)[t * 2 + 1];
    float4 la = ((const float4*)lnw)[t * 2];
    float4 lb = ((const float4*)lnw)[t * 2 + 1];

    float4 qw0[10], qw1[10];
    #pragma unroll
    for (int r = 0; r < 10; ++r) {
        const int R = b * 10 + r;
        const float* w;
        if (R < 2048)      w = wq + (size_t)R * HIDDEN;
        else if (R < 2304) w = wk + (size_t)(R - 2048) * HIDDEN;
        else               w = wv + (size_t)(R - 2304) * HIDDEN;
        qw0[r] = ((const float4*)w)[t * 2];
        qw1[r] = ((const float4*)w)[t * 2 + 1];
    }

    // RoPE table (block 0 only): fp64 angle + range-reduce, then sincosf.
    // Pure VALU, overlaps the weight-load wait.
    if (b == 0 && t < 64) {
        double e = (double)t * (1.0 / 64.0);
        double invf = exp2(-19.931568569324174087 * e);   /* 1e6^-e */
        double a = (double)curpos[0] * invf;
        a -= 6.2831853071795864769 * floor(a * 0.15915494309189533577);
        float s, c;
        sincosf((float)a, &s, &c);
        ws[WS_TAB + t] = c;
        ws[WS_TAB + 64 + t] = s;
    }

    // RMSNorm
    float ss = dot4(xa, xa) + dot4(xb, xb);
    #pragma unroll
    for (int m = 32; m; m >>= 1) ss += __shfl_xor(ss, m);
    if (lane == 0) redS[wid] = ss;
    __syncthreads();
    const float inv = rsqrtf((redS[0] + redS[1] + redS[2] + redS[3]) * (1.f / HIDDEN) + EPS);
    float4 nxa, nxb;
    nxa.x = xa.x * inv * la.x; nxa.y = xa.y * inv * la.y;
    nxa.z = xa.z * inv * la.z; nxa.w = xa.w * inv * la.w;
    nxb.x = xb.x * inv * lb.x; nxb.y = xb.y * inv * lb.y;
    nxb.z = xb.z * inv * lb.z; nxb.w = xb.w * inv * lb.w;

    // 10 block-wide dots
    float p[10];
    #pragma unroll
    for (int r = 0; r < 10; ++r)
        p[r] = dot4(qw0[r], nxa) + dot4(qw1[r], nxb);
    #pragma unroll
    for (int r = 0; r < 10; ++r)
        #pragma unroll
        for (int m = 32; m; m >>= 1) p[r] += __shfl_xor(p[r], m);
    if (lane == 0)
        #pragma unroll
        for (int r = 0; r < 10; ++r) redR[wid][r] = p[r];
    __syncthreads();
    if (t < 10) {
        const int R = b * 10 + t;
        float bias;
        if (R < 2048)      bias = bq[R];
        else if (R < 2304) bias = bk[R - 2048];
        else               bias = bv[R - 2304];
        ws[R] = redR[0][t] + redR[1][t] + redR[2][t] + redR[3][t] + bias;
    }
}

// ------------------------------------------- K2: attn partials (128 blocks)
// HPB=8 (one KV head per block-group), CHUNK=64: K/V read exactly once.
__global__ __launch_bounds__(256, 1) void attn_kernel(
    const float* __restrict__ kvc, const int* __restrict__ curpos,
    float* __restrict__ ws)
{
    const int pos = curpos[0];
    const int grp = blockIdx.x >> 6;       /* KV head */
    const int c = blockIdx.x & 63;
    const int start = c * CHUNK;
    if (start > pos) return;
    const int nvalid = min(CHUNK, pos + 1 - start);
    const int h0 = grp * HPB;
    const float* kc = kvc + (size_t)grp * CTX * HD;
    const float* vc = kvc + (size_t)(NL * NKV + grp) * CTX * HD;

    __shared__ float tab[128];
    __shared__ float kf[HD];
    __shared__ float qr[HPB][HD];
    __shared__ float sc[HPB][CHUNK];
    __shared__ float ctxh[8][HPB][HD];

    const int t = threadIdx.x;
    const int lane = t & 63, wid = t >> 6;
    const int g16 = t >> 4, li = t & 15;
    const int half = t >> 5, q4 = t & 31;

    // ---- batch-issue K tile (4x2 float4/lane) then V tile (8 float4/lane)
    float4 ka[4], kb[4];
    #pragma unroll
    for (int it = 0; it < 4; ++it) {
        const int pp = start + it * 16 + g16;    // < CTX, always in-bounds
        const float4* kp = (const float4*)(kc + (size_t)pp * HD + li * 8);
        ka[it] = kp[0]; kb[it] = kp[1];
    }
    float4 vv[8];
    #pragma unroll
    for (int i = 0; i < 8; ++i) {
        const int pp = start + i * 8 + half;
        vv[i] = ((const float4*)(vc + (size_t)pp * HD))[q4];
    }

    // ---- small ws reads + RoPE while K/V stream
    if (t < 128) tab[t] = ws[WS_TAB + t];
    __syncthreads();
    if (t < 128) {  // fresh k, roped
        const float* kr = ws + 2048 + (size_t)grp * HD;
        float kvd = kr[t], kp = kr[t ^ 64];
        float r = (t < 64) ? -kp : kp;
        kf[t] = kvd * tab[t & 63] + r * tab[64 + (t & 63)];
    }
    #pragma unroll
    for (int i = 0; i < 4; ++i) {  // q RoPE + scale (8 heads x 128)
        int e = t + i * 256;
        int hh = e >> 7, d = e & 127;
        const float* q = ws + (size_t)(h0 + hh) * HD;
        float qv = q[d], qp = q[d ^ 64];
        float r = (d < 64) ? -qp : qp;
        qr[hh][d] = (qv * tab[d & 63] + r * tab[64 + (d & 63)]) * RSQRT_HD;
    }
    __syncthreads();
    float4 fv = ((const float4*)(ws + 2304 + (size_t)grp * HD))[q4];

    // ---- scores: two passes of 4 heads over the same K registers
    #pragma unroll
    for (int P = 0; P < 2; ++P) {
        float4 qa[4], qb[4];
        #pragma unroll
        for (int hh = 0; hh < 4; ++hh) {
            qa[hh] = *(const float4*)&qr[P * 4 + hh][li * 8];
            qb[hh] = *(const float4*)&qr[P * 4 + hh][li * 8 + 4];
        }
        #pragma unroll
        for (int it = 0; it < 4; ++it) {
            const int pl = it * 16 + g16;
            float4 A = ka[it], B = kb[it];
            if (start + pl == pos) {
                A = *(const float4*)&kf[li * 8];
                B = *(const float4*)&kf[li * 8 + 4];
            }
            float s0 = dot4(qa[0], A) + dot4(qb[0], B);
            float s1 = dot4(qa[1], A) + dot4(qb[1], B);
            float s2 = dot4(qa[2], A) + dot4(qb[2], B);
            float s3 = dot4(qa[3], A) + dot4(qb[3], B);
            #pragma unroll
            for (int m = 1; m < 16; m <<= 1) {
                s0 += __shfl_xor(s0, m); s1 += __shfl_xor(s1, m);
                s2 += __shfl_xor(s2, m); s3 += __shfl_xor(s3, m);
            }
            if (pl < nvalid && li == 0) {
                sc[P * 4 + 0][pl] = s0; sc[P * 4 + 1][pl] = s1;
                sc[P * 4 + 2][pl] = s2; sc[P * 4 + 3][pl] = s3;
            }
        }
    }
    // zero invalid tail (8 heads x 64 slots, 2/thread)
    #pragma unroll
    for (int i = 0; i < 2; ++i) {
        int e = t + i * 256;
        int hh = e >> 6, pl = e & 63;
        if (pl >= nvalid) sc[hh][pl] = 0.f;
    }
    __syncthreads();

    // ---- softmax stats: wave wid -> heads wid, wid+4 (one elem per lane)
    #pragma unroll
    for (int pass = 0; pass < 2; ++pass) {
        const int hh = wid + pass * 4;
        float m = (lane < nvalid) ? sc[hh][lane] : -INFINITY;
        #pragma unroll
        for (int mm = 32; mm; mm >>= 1) m = fmaxf(m, __shfl_xor(m, mm));
        float l = 0.f;
        if (lane < nvalid) {
            l = expf(sc[hh][lane] - m);
            sc[hh][lane] = l;
        }
        #pragma unroll
        for (int mm = 32; mm; mm >>= 1) l += __shfl_xor(l, mm);
        if (lane == 0) {
            ws[WS_PML + ((size_t)(h0 + hh) * NCHUNKS + c) * 2]     = m;
            ws[WS_PML + ((size_t)(h0 + hh) * NCHUNKS + c) * 2 + 1] = l;
        }
    }
    __syncthreads();

    // ---- ctx partial from register-resident V
    #pragma unroll
    for (int P = 0; P < 2; ++P) {
        float4 a[4];
        #pragma unroll
        for (int hh = 0; hh < 4; ++hh) a[hh] = make_float4(0.f, 0.f, 0.f, 0.f);
        #pragma unroll
        for (int i = 0; i < 8; ++i) {
            const int pl = i * 8 + half;
            float4 xv = (start + pl == pos) ? fv : vv[i];
            #pragma unroll
            for (int hh = 0; hh < 4; ++hh) {
                float w = sc[P * 4 + hh][pl];
                a[hh].x += w * xv.x; a[hh].y += w * xv.y;
                a[hh].z += w * xv.z; a[hh].w += w * xv.w;
            }
        }
        #pragma unroll
        for (int hh = 0; hh < 4; ++hh)
            *(float4*)&ctxh[half][P * 4 + hh][q4 * 4] = a[hh];
    }
    __syncthreads();

    #pragma unroll
    for (int i = 0; i < 4; ++i) {
        int e = t + i * 256;
        int hh = e >> 7, d = e & 127;
        float s = 0.f;
        #pragma unroll
        for (int hf = 0; hf < 8; ++hf) s += ctxh[hf][hh][d];
        ws[WS_PACC + ((size_t)(h0 + hh) * NCHUNKS + c) * 128 + d] = s;
    }
}

// --------------------------- K3: combine + out proj + residual (256 blocks)
__global__ __launch_bounds__(256, 1) void out_kernel(
    const float* __restrict__ wo, const float* __restrict__ hidden,
    const float* __restrict__ ws, const int* __restrict__ curpos,
    float* __restrict__ out)
{
    const int t = threadIdx.x;
    const int lane = t & 63, wid = t >> 6;

    // hoist weight loads: 16 MB stream in flight during combine
    const int row0 = blockIdx.x * 8 + wid * 2;
    const float4* w04 = (const float4*)(wo + (size_t)row0 * HIDDEN);
    const float4* w14 = (const float4*)(wo + (size_t)(row0 + 1) * HIDDEN);
    float4 u[8], v[8];
    #pragma unroll
    for (int j = 0; j < 8; ++j) { u[j] = w04[j * 64 + lane]; v[j] = w14[j * 64 + lane]; }

    // redundant per-block combine: thread -> head t>>4, dims (t&15)*8..+7
    __shared__ float ctx[HIDDEN];
    const int pos = curpos[0];
    const int nc = pos / CHUNK + 1;
    const int h = t >> 4, sub = t & 15;
    float M = -INFINITY;
    for (int c2 = 0; c2 < nc; ++c2)
        M = fmaxf(M, ws[WS_PML + ((size_t)h * NCHUNKS + c2) * 2]);
    float L = 0.f;
    float4 acc0 = make_float4(0.f,0.f,0.f,0.f), acc1 = make_float4(0.f,0.f,0.f,0.f);
    for (int c2 = 0; c2 < nc; ++c2) {
        float mm = ws[WS_PML + ((size_t)h * NCHUNKS + c2) * 2];
        float ll = ws[WS_PML + ((size_t)h * NCHUNKS + c2) * 2 + 1];
        float w = expf(mm - M);
        L += w * ll;
        const float4* pa = (const float4*)(ws + WS_PACC + ((size_t)h * NCHUNKS + c2) * 128 + sub * 8);
        float4 p0 = pa[0], p1 = pa[1];
        acc0.x += w*p0.x; acc0.y += w*p0.y; acc0.z += w*p0.z; acc0.w += w*p0.w;
        acc1.x += w*p1.x; acc1.y += w*p1.y; acc1.z += w*p1.z; acc1.w += w*p1.w;
    }
    float invL = 1.f / L;
    acc0.x *= invL; acc0.y *= invL; acc0.z *= invL; acc0.w *= invL;
    acc1.x *= invL; acc1.y *= invL; acc1.z *= invL; acc1.w *= invL;
    *(float4*)&ctx[h * HD + sub * 8]     = acc0;
    *(float4*)&ctx[h * HD + sub * 8 + 4] = acc1;
    __syncthreads();

    const float4* c4 = (const float4*)ctx;
    float a0 = 0.f, a1 = 0.f;
    #pragma unroll
    for (int j = 0; j < 8; ++j) {
        float4 n = c4[j * 64 + lane];
        a0 += dot4(u[j], n);
        a1 += dot4(v[j], n);
    }
    #pragma unroll
    for (int m = 32; m; m >>= 1) { a0 += __shfl_xor(a0, m); a1 += __shfl_xor(a1, m); }
    if (lane == 0) {
        out[row0]     = hidden[row0]     + a0;
        out[row0 + 1] = hidden[row0 + 1] + a1;
    }
}

extern "C" void kernel_launch(void* const* d_in, const int* in_sizes, int n_in,
                              void* d_out, int out_size, void* d_ws, size_t ws_size,
                              hipStream_t stream)
{
    const float* hidden = (const float*)d_in[0];
    const int*   cur    = (const int*)d_in[3];
    const float* lnw    = (const float*)d_in[4];
    const float* wq     = (const float*)d_in[5];
    const float* bq     = (const float*)d_in[6];
    const float* wk     = (const float*)d_in[7];
    const float* bk     = (const float*)d_in[8];
    const float* wv     = (const float*)d_in[9];
    const float* bv     = (const float*)d_in[10];
    const float* wo     = (const float*)d_in[11];
    const float* kv     = (const float*)d_in[12];
    float* ws  = (float*)d_ws;
    float* out = (float*)d_out;

    qkv_kernel<<<dim3(256), dim3(256), 0, stream>>>(hidden, lnw, wq, bq, wk, bk, wv, bv, cur, ws);
    attn_kernel<<<dim3(NATT), dim3(256), 0, stream>>>(kv, cur, ws);
    out_kernel<<<dim3(256), dim3(256), 0, stream>>>(wo, hidden, ws, cur, out);
}

// Round 7
// 43.571 us; speedup vs baseline: 3.2176x; 1.0896x over previous
//
#include <hip/hip_runtime.h>
#include <hip/hip_bf16.h>
#include <math.h>

#define HIDDEN 2048
#define NH 16
#define NKV 2
#define HD 128
#define CTX 4096
#define NL 36
#define EPS 1e-6f

#define CHUNK 128
#define NCHUNKS 32              /* CTX/CHUNK */
#define HPB 8                   /* Q heads per attn block (= one KV head) */
#define NATT 64                 /* NKV * NCHUNKS */

/* ws layout (float offsets) */
#define WS_QRAW 0               /* 2048 */
#define WS_KRAW 2048            /* 256 */
#define WS_VRAW 2304            /* 256 */
#define WS_TAB  2560            /* cos[64], sin[64] */
#define WS_PML  2688            /* NH*NCHUNKS*2 = 1024 */
#define WS_PACC 3712            /* NH*NCHUNKS*128 = 65536 */

#define RSQRT_HD 0.08838834764831845f  /* 1/sqrt(128) */

__device__ __forceinline__ float dot4(float4 a, float4 b) {
    return a.x*b.x + a.y*b.y + a.z*b.z + a.w*b.w;
}

// ------------------------------------------------- K1: QKV (160+1 blocks)
// 16 rows/block, 4 rows/wave, R2's coalesced lane-stride-16B pattern.
// Block 160: RoPE cos/sin table only.
__global__ __launch_bounds__(256, 1) void qkv_kernel(
    const float* __restrict__ x, const float* __restrict__ lnw,
    const float* __restrict__ wq, const float* __restrict__ bq,
    const float* __restrict__ wk, const float* __restrict__ bk,
    const float* __restrict__ wv, const float* __restrict__ bv,
    const int* __restrict__ curpos, float* __restrict__ ws)
{
    const int t = threadIdx.x;
    const int lane = t & 63, wid = t >> 6;
    const int b = blockIdx.x;

    if (b == 160) {
        if (t < 64) {
            double e = (double)t * (1.0 / 64.0);
            double invf = exp2(-19.931568569324174087 * e);   /* 1e6^-e */
            double a = (double)curpos[0] * invf;
            a -= 6.2831853071795864769 * floor(a * 0.15915494309189533577);
            float s, c;
            sincosf((float)a, &s, &c);
            ws[WS_TAB + t] = c;
            ws[WS_TAB + 64 + t] = s;
        }
        return;
    }

    // row pointers for this wave's 4 rows
    const int R0 = b * 16 + wid * 4;
    const float* wr[4]; float bias[4];
    #pragma unroll
    for (int r = 0; r < 4; ++r) {
        const int R = R0 + r;
        if (R < 2048)      { wr[r] = wq + (size_t)R * HIDDEN;            bias[r] = bq[R]; }
        else if (R < 2304) { wr[r] = wk + (size_t)(R - 2048) * HIDDEN;   bias[r] = bk[R - 2048]; }
        else               { wr[r] = wv + (size_t)(R - 2304) * HIDDEN;   bias[r] = bv[R - 2304]; }
    }

    // issue x/lnw then 4x8 coalesced weight float4s (128 VGPRs, 32KB/wave)
    float4 xa = ((const float4*)x)[t * 2];
    float4 xb = ((const float4*)x)[t * 2 + 1];
    float4 la = ((const float4*)lnw)[t * 2];
    float4 lb = ((const float4*)lnw)[t * 2 + 1];
    float4 u[4][8];
    #pragma unroll
    for (int r = 0; r < 4; ++r)
        #pragma unroll
        for (int j = 0; j < 8; ++j)
            u[r][j] = ((const float4*)wr[r])[j * 64 + lane];

    // RMSNorm
    __shared__ float nx[HIDDEN];
    __shared__ float redS[4];
    float ss = dot4(xa, xa) + dot4(xb, xb);
    #pragma unroll
    for (int m = 32; m; m >>= 1) ss += __shfl_xor(ss, m);
    if (lane == 0) redS[wid] = ss;
    __syncthreads();
    const float inv = rsqrtf((redS[0] + redS[1] + redS[2] + redS[3]) * (1.f / HIDDEN) + EPS);
    float4 na, nb;
    na.x = xa.x * inv * la.x; na.y = xa.y * inv * la.y;
    na.z = xa.z * inv * la.z; na.w = xa.w * inv * la.w;
    nb.x = xb.x * inv * lb.x; nb.y = xb.y * inv * lb.y;
    nb.z = xb.z * inv * lb.z; nb.w = xb.w * inv * lb.w;
    ((float4*)nx)[t * 2] = na;
    ((float4*)nx)[t * 2 + 1] = nb;
    __syncthreads();

    // 4 dots per wave
    const float4* nx4 = (const float4*)nx;
    float a[4] = {0.f, 0.f, 0.f, 0.f};
    #pragma unroll
    for (int j = 0; j < 8; ++j) {
        float4 n = nx4[j * 64 + lane];
        #pragma unroll
        for (int r = 0; r < 4; ++r) a[r] += dot4(u[r][j], n);
    }
    #pragma unroll
    for (int r = 0; r < 4; ++r)
        #pragma unroll
        for (int m = 32; m; m >>= 1) a[r] += __shfl_xor(a[r], m);
    if (lane == 0) {
        #pragma unroll
        for (int r = 0; r < 4; ++r) ws[R0 + r] = a[r] + bias[r];
    }
}

// --------------------------------------------- K2: attn partials (64 blocks)
// HPB=8 (K/V read exactly once), CHUNK=128, batch-issued K/V tiles.
// Small ws loads issued BEFORE K/V so RoPE overlaps the stream (in-order vmcnt).
__global__ __launch_bounds__(256, 1) void attn_kernel(
    const float* __restrict__ kvc, const int* __restrict__ curpos,
    float* __restrict__ ws)
{
    const int pos = curpos[0];
    const int grp = blockIdx.x >> 5;       /* KV head */
    const int c = blockIdx.x & 31;
    const int start = c * CHUNK;
    if (start > pos) return;
    const int nvalid = min(CHUNK, pos + 1 - start);
    const int h0 = grp * HPB;
    const float* kc = kvc + (size_t)grp * CTX * HD;
    const float* vc = kvc + (size_t)(NL * NKV + grp) * CTX * HD;

    __shared__ float tab[128];
    __shared__ float kf[HD];
    __shared__ float qr[HPB][HD];
    __shared__ float sc[HPB][CHUNK];
    __shared__ float ctxh[8][HPB][HD];

    const int t = threadIdx.x;
    const int lane = t & 63, wid = t >> 6;
    const int g16 = t >> 4, li = t & 15;
    const int half = t >> 5, q4 = t & 31;

    // ---- (1) small ws loads into registers (L2-resident, ~11 loads)
    float tabv = 0.f;
    if (t < 128) tabv = ws[WS_TAB + t];
    float krv = 0.f, krp = 0.f;
    if (t < 128) {
        const float* kr = ws + WS_KRAW + (size_t)grp * HD;
        krv = kr[t]; krp = kr[t ^ 64];
    }
    float qv[4], qp[4];
    #pragma unroll
    for (int i = 0; i < 4; ++i) {
        int e = t + i * 256;
        int hh = e >> 7, d = e & 127;
        const float* q = ws + WS_QRAW + (size_t)(h0 + hh) * HD;
        qv[i] = q[d]; qp[i] = q[d ^ 64];
    }
    float4 fv = ((const float4*)(ws + WS_VRAW + (size_t)grp * HD))[q4];

    // ---- (2) batch-issue K tile (16 float4) then V tile (16 float4)
    float4 ka[8], kb[8];
    #pragma unroll
    for (int it = 0; it < 8; ++it) {
        const int pp = start + it * 16 + g16;    // < CTX, always in-bounds
        const float4* kp = (const float4*)(kc + (size_t)pp * HD + li * 8);
        ka[it] = kp[0]; kb[it] = kp[1];
    }
    float4 vv[16];
    #pragma unroll
    for (int i = 0; i < 16; ++i) {
        const int pp = start + i * 8 + half;
        vv[i] = ((const float4*)(vc + (size_t)pp * HD))[q4];
    }

    // ---- (3) RoPE into LDS (waits only on the small loads)
    if (t < 128) tab[t] = tabv;
    __syncthreads();
    if (t < 128) {
        float r = (t < 64) ? -krp : krp;
        kf[t] = krv * tab[t & 63] + r * tab[64 + (t & 63)];
    }
    #pragma unroll
    for (int i = 0; i < 4; ++i) {
        int e = t + i * 256;
        int hh = e >> 7, d = e & 127;
        float r = (d < 64) ? -qp[i] : qp[i];
        qr[hh][d] = (qv[i] * tab[d & 63] + r * tab[64 + (d & 63)]) * RSQRT_HD;
    }
    __syncthreads();

    // ---- (4) scores: two passes of 4 heads over the same K registers
    #pragma unroll
    for (int P = 0; P < 2; ++P) {
        float4 qa[4], qb[4];
        #pragma unroll
        for (int hh = 0; hh < 4; ++hh) {
            qa[hh] = *(const float4*)&qr[P * 4 + hh][li * 8];
            qb[hh] = *(const float4*)&qr[P * 4 + hh][li * 8 + 4];
        }
        #pragma unroll
        for (int it = 0; it < 8; ++it) {
            const int pl = it * 16 + g16;
            float4 A = ka[it], B = kb[it];
            if (start + pl == pos) {
                A = *(const float4*)&kf[li * 8];
                B = *(const float4*)&kf[li * 8 + 4];
            }
            float s0 = dot4(qa[0], A) + dot4(qb[0], B);
            float s1 = dot4(qa[1], A) + dot4(qb[1], B);
            float s2 = dot4(qa[2], A) + dot4(qb[2], B);
            float s3 = dot4(qa[3], A) + dot4(qb[3], B);
            #pragma unroll
            for (int m = 1; m < 16; m <<= 1) {
                s0 += __shfl_xor(s0, m); s1 += __shfl_xor(s1, m);
                s2 += __shfl_xor(s2, m); s3 += __shfl_xor(s3, m);
            }
            if (pl < nvalid && li == 0) {
                sc[P * 4 + 0][pl] = s0; sc[P * 4 + 1][pl] = s1;
                sc[P * 4 + 2][pl] = s2; sc[P * 4 + 3][pl] = s3;
            }
        }
    }
    // zero invalid tail (8 heads x 128 slots, 4/thread)
    #pragma unroll
    for (int i = 0; i < 4; ++i) {
        int e = t + i * 256;
        int hh = e >> 7, pl = e & 127;
        if (pl >= nvalid) sc[hh][pl] = 0.f;
    }
    __syncthreads();

    // ---- (5) softmax stats: wave wid -> heads wid, wid+4
    #pragma unroll
    for (int pass = 0; pass < 2; ++pass) {
        const int hh = wid + pass * 4;
        float m = -INFINITY;
        for (int pp = lane; pp < nvalid; pp += 64) m = fmaxf(m, sc[hh][pp]);
        #pragma unroll
        for (int mm = 32; mm; mm >>= 1) m = fmaxf(m, __shfl_xor(m, mm));
        float l = 0.f;
        for (int pp = lane; pp < nvalid; pp += 64) {
            float e = expf(sc[hh][pp] - m);
            sc[hh][pp] = e;
            l += e;
        }
        #pragma unroll
        for (int mm = 32; mm; mm >>= 1) l += __shfl_xor(l, mm);
        if (lane == 0) {
            ws[WS_PML + ((size_t)(h0 + hh) * NCHUNKS + c) * 2]     = m;
            ws[WS_PML + ((size_t)(h0 + hh) * NCHUNKS + c) * 2 + 1] = l;
        }
    }
    __syncthreads();

    // ---- (6) ctx partial from register-resident V
    #pragma unroll
    for (int P = 0; P < 2; ++P) {
        float4 a[4];
        #pragma unroll
        for (int hh = 0; hh < 4; ++hh) a[hh] = make_float4(0.f, 0.f, 0.f, 0.f);
        #pragma unroll
        for (int i = 0; i < 16; ++i) {
            const int pl = i * 8 + half;
            float4 xv = (start + pl == pos) ? fv : vv[i];
            #pragma unroll
            for (int hh = 0; hh < 4; ++hh) {
                float w = sc[P * 4 + hh][pl];
                a[hh].x += w * xv.x; a[hh].y += w * xv.y;
                a[hh].z += w * xv.z; a[hh].w += w * xv.w;
            }
        }
        #pragma unroll
        for (int hh = 0; hh < 4; ++hh)
            *(float4*)&ctxh[half][P * 4 + hh][q4 * 4] = a[hh];
    }
    __syncthreads();

    #pragma unroll
    for (int i = 0; i < 4; ++i) {
        int e = t + i * 256;
        int hh = e >> 7, d = e & 127;
        float s = 0.f;
        #pragma unroll
        for (int hf = 0; hf < 8; ++hf) s += ctxh[hf][hh][d];
        ws[WS_PACC + ((size_t)(h0 + hh) * NCHUNKS + c) * 128 + d] = s;
    }
}

// --------------------------- K3: combine + out proj + residual (256 blocks)
__global__ __launch_bounds__(256, 1) void out_kernel(
    const float* __restrict__ wo, const float* __restrict__ hidden,
    const float* __restrict__ ws, const int* __restrict__ curpos,
    float* __restrict__ out)
{
    const int t = threadIdx.x;
    const int lane = t & 63, wid = t >> 6;

    // hoist weight loads: 16 MB stream in flight during combine
    const int row0 = blockIdx.x * 8 + wid * 2;
    const float4* w04 = (const float4*)(wo + (size_t)row0 * HIDDEN);
    const float4* w14 = (const float4*)(wo + (size_t)(row0 + 1) * HIDDEN);
    float4 u[8], v[8];
    #pragma unroll
    for (int j = 0; j < 8; ++j) { u[j] = w04[j * 64 + lane]; v[j] = w14[j * 64 + lane]; }

    // redundant per-block combine: thread -> head t>>4, dims (t&15)*8..+7
    __shared__ float ctx[HIDDEN];
    const int pos = curpos[0];
    const int nc = pos / CHUNK + 1;
    const int h = t >> 4, sub = t & 15;
    float M = -INFINITY;
    for (int c2 = 0; c2 < nc; ++c2)
        M = fmaxf(M, ws[WS_PML + ((size_t)h * NCHUNKS + c2) * 2]);
    float L = 0.f;
    float4 acc0 = make_float4(0.f,0.f,0.f,0.f), acc1 = make_float4(0.f,0.f,0.f,0.f);
    for (int c2 = 0; c2 < nc; ++c2) {
        float mm = ws[WS_PML + ((size_t)h * NCHUNKS + c2) * 2];
        float ll = ws[WS_PML + ((size_t)h * NCHUNKS + c2) * 2 + 1];
        float w = expf(mm - M);
        L += w * ll;
        const float4* pa = (const float4*)(ws + WS_PACC + ((size_t)h * NCHUNKS + c2) * 128 + sub * 8);
        float4 p0 = pa[0], p1 = pa[1];
        acc0.x += w*p0.x; acc0.y += w*p0.y; acc0.z += w*p0.z; acc0.w += w*p0.w;
        acc1.x += w*p1.x; acc1.y += w*p1.y; acc1.z += w*p1.z; acc1.w += w*p1.w;
    }
    float invL = 1.f / L;
    acc0.x *= invL; acc0.y *= invL; acc0.z *= invL; acc0.w *= invL;
    acc1.x *= invL; acc1.y *= invL; acc1.z *= invL; acc1.w *= invL;
    *(float4*)&ctx[h * HD + sub * 8]     = acc0;
    *(float4*)&ctx[h * HD + sub * 8 + 4] = acc1;
    __syncthreads();

    const float4* c4 = (const float4*)ctx;
    float a0 = 0.f, a1 = 0.f;
    #pragma unroll
    for (int j = 0; j < 8; ++j) {
        float4 n = c4[j * 64 + lane];
        a0 += dot4(u[j], n);
        a1 += dot4(v[j], n);
    }
    #pragma unroll
    for (int m = 32; m; m >>= 1) { a0 += __shfl_xor(a0, m); a1 += __shfl_xor(a1, m); }
    if (lane == 0) {
        out[row0]     = hidden[row0]     + a0;
        out[row0 + 1] = hidden[row0 + 1] + a1;
    }
}

extern "C" void kernel_launch(void* const* d_in, const int* in_sizes, int n_in,
                              void* d_out, int out_size, void* d_ws, size_t ws_size,
                              hipStream_t stream)
{
    const float* hidden = (const float*)d_in[0];
    const int*   cur    = (const int*)d_in[3];
    const float* lnw    = (const float*)d_in[4];
    const float* wq     = (const float*)d_in[5];
    const float* bq     = (const float*)d_in[6];
    const float* wk     = (const float*)d_in[7];
    const float* bk     = (const float*)d_in[8];
    const float* wv     = (const float*)d_in[9];
    const float* bv     = (const float*)d_in[10];
    const float* wo     = (const float*)d_in[11];
    const float* kv     = (const float*)d_in[12];
    float* ws  = (float*)d_ws;
    float* out = (float*)d_out;

    qkv_kernel<<<dim3(161), dim3(256), 0, stream>>>(hidden, lnw, wq, bq, wk, bk, wv, bv, cur, ws);
    attn_kernel<<<dim3(NATT), dim3(256), 0, stream>>>(kv, cur, ws);
    out_kernel<<<dim3(256), dim3(256), 0, stream>>>(wo, hidden, ws, cur, out);
}